// Round 1
// baseline (587.875 us; speedup 1.0000x reference)
//
#include <hip/hip_runtime.h>
#include <math.h>

// Dims (CLEVR-scale, fixed)
#define BB 128
#define NN 36
#define DF 512
#define DE 256
#define DV 512
#define HH 256
#define NCC 28
#define LQ 5
#define NE 1296           // N*N edges per batch
#define SCALE 0.04419417382415922f   // 1/sqrt(512)

typedef __bf16 bf16_8 __attribute__((ext_vector_type(8)));
typedef float  f32_4  __attribute__((ext_vector_type(4)));

__device__ __forceinline__ float sigmoidf_(float x){ return 1.0f/(1.0f + expf(-x)); }
__device__ __forceinline__ float reluf_(float x){ return x > 0.f ? x : 0.f; }

// ---------------------------------------------------------------------------
// K1: per-batch: gather q0..q3 rows; ve[b][h] = W_e2[h,:]·q2 ; se[b] = b_e2·q2
// ---------------------------------------------------------------------------
__global__ __launch_bounds__(256) void k_prep(
    const float* __restrict__ word_emb, const int* __restrict__ program_inputs,
    const float* __restrict__ W_e2, const float* __restrict__ b_e2,
    float* __restrict__ qws, float* __restrict__ ve, float* __restrict__ se)
{
    int b = blockIdx.x, t = threadIdx.x;
    int idx[4];
    #pragma unroll
    for (int k=0;k<4;k++) idx[k] = program_inputs[b*LQ + k];
    #pragma unroll
    for (int k=0;k<4;k++){
        qws[((size_t)(b*4+k))*DV + t]       = word_emb[(size_t)idx[k]*DV + t];
        qws[((size_t)(b*4+k))*DV + t + 256] = word_emb[(size_t)idx[k]*DV + t + 256];
    }
    const float* q2 = word_emb + (size_t)idx[2]*DV;
    const float* wrow = W_e2 + (size_t)t*DV;     // W_e2 is [H,DV] row-major
    float acc = 0.f;
    for (int d=0; d<DV; d+=4){
        float4 w = *(const float4*)(wrow + d);
        float4 q = *(const float4*)(q2 + d);
        acc += w.x*q.x + w.y*q.y + w.z*q.z + w.w*q.w;
    }
    ve[b*HH + t] = acc;
    // se = b_e2 . q2  (b_e2 is zeros in setup, but compute it anyway)
    float p = b_e2[t]*q2[t] + b_e2[t+256]*q2[t+256];
    __shared__ float red[4];
    #pragma unroll
    for (int off=32; off; off>>=1) p += __shfl_down(p, off, 64);
    if ((t&63)==0) red[t>>6] = p;
    __syncthreads();
    if (t==0) se[b] = red[0]+red[1]+red[2]+red[3];
}

// ---------------------------------------------------------------------------
// K2: pack W_e1 [DE=256 x H=256] fp32 -> bf16 in MFMA B-fragment order:
//   packed[((kt*16+nt)*64+lane)*8 + j] = bf16(W_e1[(kt*32+(lane>>4)*8+j)*HH + nt*16+(lane&15)])
// grid: 32 x 256 = 8192 threads
// ---------------------------------------------------------------------------
__global__ __launch_bounds__(256) void k_pack_we1(const float* __restrict__ W_e1,
                                                  __bf16* __restrict__ packed)
{
    int g = blockIdx.x*256 + threadIdx.x;   // 0..8191
    int kt   = g >> 10;
    int nt   = (g >> 6) & 15;
    int lane = g & 63;
    int krow = kt*32 + (lane>>4)*8;
    int ncol = nt*16 + (lane&15);
    __bf16* dst = packed + (size_t)g*8;
    #pragma unroll
    for (int j=0;j<8;j++)
        dst[j] = (__bf16)(W_e1[(size_t)(krow+j)*HH + ncol]);
}

// ---------------------------------------------------------------------------
// K3a: hid = relu(node_feats @ W_n1 + b_n1)   [4608,512]@[512,256]
// 16 rows/block, thread t owns column h=t. fp32.
// ---------------------------------------------------------------------------
__global__ __launch_bounds__(256) void k_node1(
    const float* __restrict__ X, const float* __restrict__ W1,
    const float* __restrict__ b1, float* __restrict__ hid)
{
    __shared__ float xs[16][DF];   // 32 KB
    int r0 = blockIdx.x*16, t = threadIdx.x;
    #pragma unroll
    for (int i=0;i<8;i++){
        int idx = t + i*256;                 // 2048 float4
        int row = idx >> 7, c4 = idx & 127;
        *(float4*)&xs[row][c4*4] = *(const float4*)(X + (size_t)(r0+row)*DF + c4*4);
    }
    __syncthreads();
    float acc[16];
    #pragma unroll
    for (int r=0;r<16;r++) acc[r]=0.f;
    for (int k=0;k<DF;k+=4){
        float w0 = W1[(size_t)(k+0)*HH + t];
        float w1 = W1[(size_t)(k+1)*HH + t];
        float w2 = W1[(size_t)(k+2)*HH + t];
        float w3 = W1[(size_t)(k+3)*HH + t];
        #pragma unroll
        for (int r=0;r<16;r++){
            float4 xv = *(const float4*)&xs[r][k];
            acc[r] = fmaf(xv.x,w0,fmaf(xv.y,w1,fmaf(xv.z,w2,fmaf(xv.w,w3,acc[r]))));
        }
    }
    float bias = b1[t];
    #pragma unroll
    for (int r=0;r<16;r++)
        hid[(size_t)(r0+r)*HH + t] = reluf_(acc[r] + bias);
}

// ---------------------------------------------------------------------------
// K3b: nf = hid @ W_n2 + b_n2   [4608,256]@[256,512]
// 16 rows/block, thread t owns columns d=t and d=t+256. fp32.
// ---------------------------------------------------------------------------
__global__ __launch_bounds__(256) void k_node2(
    const float* __restrict__ hid, const float* __restrict__ W2,
    const float* __restrict__ b2, float* __restrict__ nf)
{
    __shared__ float hs[16][HH];   // 16 KB
    int r0 = blockIdx.x*16, t = threadIdx.x;
    #pragma unroll
    for (int i=0;i<4;i++){
        int idx = t + i*256;                 // 1024 float4
        int row = idx >> 6, c4 = idx & 63;
        *(float4*)&hs[row][c4*4] = *(const float4*)(hid + (size_t)(r0+row)*HH + c4*4);
    }
    __syncthreads();
    float acc0[16], acc1[16];
    #pragma unroll
    for (int r=0;r<16;r++){acc0[r]=0.f;acc1[r]=0.f;}
    for (int h=0; h<HH; h+=4){
        float w00 = W2[(size_t)(h+0)*DV + t], w01 = W2[(size_t)(h+0)*DV + t + 256];
        float w10 = W2[(size_t)(h+1)*DV + t], w11 = W2[(size_t)(h+1)*DV + t + 256];
        float w20 = W2[(size_t)(h+2)*DV + t], w21 = W2[(size_t)(h+2)*DV + t + 256];
        float w30 = W2[(size_t)(h+3)*DV + t], w31 = W2[(size_t)(h+3)*DV + t + 256];
        #pragma unroll
        for (int r=0;r<16;r++){
            float4 hv = *(const float4*)&hs[r][h];
            acc0[r] = fmaf(hv.x,w00,fmaf(hv.y,w10,fmaf(hv.z,w20,fmaf(hv.w,w30,acc0[r]))));
            acc1[r] = fmaf(hv.x,w01,fmaf(hv.y,w11,fmaf(hv.z,w21,fmaf(hv.w,w31,acc1[r]))));
        }
    }
    float bb0 = b2[t], bb1 = b2[t+256];
    #pragma unroll
    for (int r=0;r<16;r++){
        nf[(size_t)(r0+r)*DV + t]       = acc0[r] + bb0;
        nf[(size_t)(r0+r)*DV + t + 256] = acc1[r] + bb1;
    }
}

// ---------------------------------------------------------------------------
// K4: edge kernel. Per block: 48 edges of one batch (1296 = 27*48 exact).
// hidden = relu(E_tile[48x256]_bf16 @ W_e1_bf16 + b_e1); logit = hidden·ve + se
// weit = sigmoid(logit*SCALE). MFMA 16x16x32 bf16, fp32 accum.
// ---------------------------------------------------------------------------
__global__ __launch_bounds__(256) void k_edge(
    const float* __restrict__ E, const __bf16* __restrict__ Wp,
    const float* __restrict__ b_e1, const float* __restrict__ ve,
    const float* __restrict__ se, float* __restrict__ weit)
{
    constexpr int LDW = DE + 8;                 // +16B pad: 2-way LDS aliasing only
    __shared__ __align__(16) __bf16 as[48*LDW]; // ~25 KB
    __shared__ float red[4][48];
    int bx = blockIdx.x;
    int b = bx / 27, tile = bx % 27;
    int e0 = tile*48;
    int t = threadIdx.x, wv = t>>6, lane = t&63;
    const float* Eb = E + ((size_t)b*NE + e0)*DE;

    // stage 48x256 fp32 -> bf16 LDS (each thread: 6 chunks of 8 floats)
    #pragma unroll
    for (int i=0;i<6;i++){
        int c = t + i*256;                      // 1536 chunks
        int row = c >> 5, cc = c & 31;
        const float* src = Eb + (size_t)row*DE + cc*8;
        float4 f0 = *(const float4*)(src);
        float4 f1 = *(const float4*)(src+4);
        bf16_8 v;
        v[0]=(__bf16)f0.x; v[1]=(__bf16)f0.y; v[2]=(__bf16)f0.z; v[3]=(__bf16)f0.w;
        v[4]=(__bf16)f1.x; v[5]=(__bf16)f1.y; v[6]=(__bf16)f1.z; v[7]=(__bf16)f1.w;
        *(bf16_8*)&as[row*LDW + cc*8] = v;
    }
    __syncthreads();

    f32_4 zero = {0.f,0.f,0.f,0.f};
    f32_4 acc[3][4];
    #pragma unroll
    for (int mt=0;mt<3;mt++)
        #pragma unroll
        for (int nt=0;nt<4;nt++) acc[mt][nt] = zero;

    int arow = lane & 15, ako = (lane>>4)*8;
    for (int kt=0; kt<8; kt++){
        bf16_8 afrag[3];
        #pragma unroll
        for (int mt=0;mt<3;mt++)
            afrag[mt] = *(const bf16_8*)&as[(mt*16 + arow)*LDW + kt*32 + ako];
        #pragma unroll
        for (int nt=0;nt<4;nt++){
            bf16_8 bfrag = *(const bf16_8*)(Wp + ((size_t)(kt*16 + (wv*4+nt))*64 + lane)*8);
            #pragma unroll
            for (int mt=0;mt<3;mt++)
                acc[mt][nt] = __builtin_amdgcn_mfma_f32_16x16x32_bf16(afrag[mt], bfrag, acc[mt][nt], 0,0,0);
        }
    }

    // epilogue: relu(+bias) then dot with ve over this wave's 64 n-columns
    float ves[4], be[4];
    #pragma unroll
    for (int nt=0;nt<4;nt++){
        int n = wv*64 + nt*16 + (lane&15);
        ves[nt] = ve[b*HH + n];
        be[nt]  = b_e1[n];
    }
    float part[3][4];   // [mt][reg(row)]
    #pragma unroll
    for (int mt=0;mt<3;mt++)
        #pragma unroll
        for (int r=0;r<4;r++){
            float s = 0.f;
            #pragma unroll
            for (int nt=0;nt<4;nt++)
                s = fmaf(reluf_(acc[mt][nt][r] + be[nt]), ves[nt], s);
            part[mt][r] = s;
        }
    // reduce across 16 columns (lane bits 0..3)
    #pragma unroll
    for (int off=1; off<16; off<<=1)
        #pragma unroll
        for (int mt=0;mt<3;mt++)
            #pragma unroll
            for (int r=0;r<4;r++)
                part[mt][r] += __shfl_xor(part[mt][r], off, 64);
    if ((lane&15)==0){
        int g = lane>>4;
        #pragma unroll
        for (int mt=0;mt<3;mt++)
            #pragma unroll
            for (int r=0;r<4;r++)
                red[wv][mt*16 + g*4 + r] = part[mt][r];
    }
    __syncthreads();
    if (t < 48){
        float logit = red[0][t]+red[1][t]+red[2][t]+red[3][t] + se[b];
        weit[(size_t)b*NE + e0 + t] = sigmoidf_(logit * SCALE);
    }
}

// ---------------------------------------------------------------------------
// K5: per-batch attention chain + query + classifier. 1 block / batch. fp32.
// ---------------------------------------------------------------------------
__global__ __launch_bounds__(256) void k_final(
    const float* __restrict__ nf, const float* __restrict__ qws,
    const float* __restrict__ weit,
    const float* __restrict__ W_q, const float* __restrict__ b_q,
    const float* __restrict__ W_c1, const float* __restrict__ b_c1,
    const float* __restrict__ W_c2, const float* __restrict__ b_c2,
    float* __restrict__ out)
{
    int b = blockIdx.x, t = threadIdx.x;
    int wv = t>>6, lane = t&63;
    __shared__ float a1[NN], a2[NN], a3[NN];
    __shared__ float xbuf[DV], obuf[DV], hbuf[HH];
    __shared__ float denom;
    const float* nfb = nf + (size_t)b*NN*DV;
    const float* q0 = qws + ((size_t)(b*4+0))*DV;
    const float* q1 = qws + ((size_t)(b*4+1))*DV;
    const float* q3 = qws + ((size_t)(b*4+3))*DV;

    // attn1[i] = sigmoid((nf_i . q3)*scale)   (scene attention is all-ones)
    for (int i=wv; i<NN; i+=4){
        const float* row = nfb + (size_t)i*DV + lane*8;
        const float* qq  = q3 + lane*8;
        float4 x0 = *(const float4*)row, x1 = *(const float4*)(row+4);
        float4 y0 = *(const float4*)qq,  y1 = *(const float4*)(qq+4);
        float p = x0.x*y0.x + x0.y*y0.y + x0.z*y0.z + x0.w*y0.w
                + x1.x*y1.x + x1.y*y1.y + x1.z*y1.z + x1.w*y1.w;
        #pragma unroll
        for (int off=32; off; off>>=1) p += __shfl_xor(p, off, 64);
        if (lane==0) a1[i] = sigmoidf_(p*SCALE);
    }
    __syncthreads();
    // attn2[j] = clip(sum_i a1[i]*weit[i][j], 0, 1)
    if (t < NN){
        const float* wrow = weit + (size_t)b*NE;
        float s = 0.f;
        for (int i=0;i<NN;i++) s = fmaf(a1[i], wrow[i*NN + t], s);
        a2[t] = fminf(fmaxf(s, 0.f), 1.f);
    }
    __syncthreads();
    // attn3[i] = a2[i]*sigmoid((nf_i . q1)*scale)
    for (int i=wv; i<NN; i+=4){
        const float* row = nfb + (size_t)i*DV + lane*8;
        const float* qq  = q1 + lane*8;
        float4 x0 = *(const float4*)row, x1 = *(const float4*)(row+4);
        float4 y0 = *(const float4*)qq,  y1 = *(const float4*)(qq+4);
        float p = x0.x*y0.x + x0.y*y0.y + x0.z*y0.z + x0.w*y0.w
                + x1.x*y1.x + x1.y*y1.y + x1.z*y1.z + x1.w*y1.w;
        #pragma unroll
        for (int off=32; off; off>>=1) p += __shfl_xor(p, off, 64);
        if (lane==0) a3[i] = a2[i]*sigmoidf_(p*SCALE);
    }
    __syncthreads();
    if (t==0){
        float s = 0.f;
        for (int i=0;i<NN;i++) s += a3[i];
        denom = 1.f/(s + 1e-8f);
    }
    __syncthreads();
    // pooled*q0
    {
        float p0=0.f, p1=0.f;
        for (int i=0;i<NN;i++){
            float a = a3[i]*denom;
            p0 = fmaf(a, nfb[(size_t)i*DV + t], p0);
            p1 = fmaf(a, nfb[(size_t)i*DV + t + 256], p1);
        }
        xbuf[t]       = p0*q0[t];
        xbuf[t+256]   = p1*q0[t+256];
    }
    __syncthreads();
    // out = relu(x @ W_q + b_q)
    {
        float o0=0.f, o1=0.f;
        for (int d=0; d<DV; d++){
            float x = xbuf[d];
            o0 = fmaf(x, W_q[(size_t)d*DV + t], o0);
            o1 = fmaf(x, W_q[(size_t)d*DV + t + 256], o1);
        }
        obuf[t]     = reluf_(o0 + b_q[t]);
        obuf[t+256] = reluf_(o1 + b_q[t+256]);
    }
    __syncthreads();
    // h = relu(out @ W_c1 + b_c1)
    {
        float h0 = 0.f;
        for (int d=0; d<DV; d++) h0 = fmaf(obuf[d], W_c1[(size_t)d*HH + t], h0);
        hbuf[t] = reluf_(h0 + b_c1[t]);
    }
    __syncthreads();
    // logits = h @ W_c2 + b_c2
    if (t < NCC){
        float s = b_c2[t];
        for (int h2=0; h2<HH; h2++) s = fmaf(hbuf[h2], W_c2[h2*NCC + t], s);
        out[b*NCC + t] = s;
    }
}

// ---------------------------------------------------------------------------
extern "C" void kernel_launch(void* const* d_in, const int* in_sizes, int n_in,
                              void* d_out, int out_size, void* d_ws, size_t ws_size,
                              hipStream_t stream)
{
    const float* node_feats = (const float*)d_in[0];
    const float* edge_feats = (const float*)d_in[1];
    const float* W_n1 = (const float*)d_in[2];
    const float* b_n1 = (const float*)d_in[3];
    const float* W_n2 = (const float*)d_in[4];
    const float* b_n2 = (const float*)d_in[5];
    const float* W_e1 = (const float*)d_in[6];
    const float* b_e1 = (const float*)d_in[7];
    const float* W_e2 = (const float*)d_in[8];
    const float* b_e2 = (const float*)d_in[9];
    const float* W_q  = (const float*)d_in[10];
    const float* b_q  = (const float*)d_in[11];
    const float* W_c1 = (const float*)d_in[12];
    const float* b_c1 = (const float*)d_in[13];
    const float* W_c2 = (const float*)d_in[14];
    const float* b_c2 = (const float*)d_in[15];
    const float* word_emb = (const float*)d_in[16];
    // d_in[17] = programs (unused by reference)
    const int* program_inputs = (const int*)d_in[18];

    // workspace layout (all 256B-aligned) — total ~15.4 MB
    char* ws = (char*)d_ws;
    float* qws  = (float*)ws; ws += (size_t)BB*4*DV*4;     // 1 MB
    float* ve   = (float*)ws; ws += (size_t)BB*HH*4;       // 128 KB
    float* se   = (float*)ws; ws += 512;                   // B floats
    __bf16* Wp  = (__bf16*)ws; ws += (size_t)DE*HH*2;      // 128 KB
    float* hid  = (float*)ws; ws += (size_t)BB*NN*HH*4;    // 4.5 MB
    float* nf   = (float*)ws; ws += (size_t)BB*NN*DV*4;    // 9 MB
    float* weit = (float*)ws; ws += (size_t)BB*NE*4;       // 648 KB

    k_prep   <<<BB, 256, 0, stream>>>(word_emb, program_inputs, W_e2, b_e2, qws, ve, se);
    k_pack_we1<<<32, 256, 0, stream>>>(W_e1, Wp);
    k_node1  <<<(BB*NN)/16, 256, 0, stream>>>(node_feats, W_n1, b_n1, hid);
    k_node2  <<<(BB*NN)/16, 256, 0, stream>>>(hid, W_n2, b_n2, nf);
    k_edge   <<<BB*27, 256, 0, stream>>>(edge_feats, Wp, b_e1, ve, se, weit);
    k_final  <<<BB, 256, 0, stream>>>(nf, qws, weit, W_q, b_q, W_c1, b_c1, W_c2, b_c2,
                                      (float*)d_out);
}

// Round 2
// 457.485 us; speedup vs baseline: 1.2850x; 1.2850x over previous
//
#include <hip/hip_runtime.h>
#include <math.h>

// Dims (CLEVR-scale, fixed)
#define BB 128
#define NN 36
#define DF 512
#define DE 256
#define DV 512
#define HH 256
#define NCC 28
#define LQ 5
#define NE 1296           // N*N edges per batch
#define SCALE 0.04419417382415922f   // 1/sqrt(512)

typedef __bf16 bf16_8 __attribute__((ext_vector_type(8)));
typedef __bf16 bf16_4 __attribute__((ext_vector_type(4)));
typedef float  f32_4  __attribute__((ext_vector_type(4)));

__device__ __forceinline__ float sigmoidf_(float x){ return 1.0f/(1.0f + expf(-x)); }
__device__ __forceinline__ float reluf_(float x){ return x > 0.f ? x : 0.f; }

// ---------------------------------------------------------------------------
// Pack all weight matrices into MFMA B-fragment planes.
// For [K x N] row-major W: packed[(slot*64+lane)*8+j] = W[(kt*32+(lane>>4)*8+j)*N + nt*16+(lane&15)]
// with slot = kt*(N/16)+nt. hi plane = bf16(w); lo plane = bf16(w - hi).
// Block ranges: [0,64) W_n1(512x256) | [64,128) W_n2(256x512) | [128,256) W_q(512x512)
//               [256,320) W_c1(512x256) | [320,352) W_e1(256x256, hi only)
// ---------------------------------------------------------------------------
__global__ __launch_bounds__(256) void k_pack_all(
    const float* __restrict__ W_n1, const float* __restrict__ W_n2,
    const float* __restrict__ W_q,  const float* __restrict__ W_c1,
    const float* __restrict__ W_e1,
    __bf16* __restrict__ Pn1h, __bf16* __restrict__ Pn1l,
    __bf16* __restrict__ Pn2h, __bf16* __restrict__ Pn2l,
    __bf16* __restrict__ Pqh,  __bf16* __restrict__ Pql,
    __bf16* __restrict__ Pc1h, __bf16* __restrict__ Pc1l,
    __bf16* __restrict__ Peh)
{
    int bid = blockIdx.x;
    const float* W; __bf16 *Ph, *Pl; int N, base;
    if (bid < 64)       { W=W_n1; Ph=Pn1h; Pl=Pn1l; N=256; base=0;   }
    else if (bid < 128) { W=W_n2; Ph=Pn2h; Pl=Pn2l; N=512; base=64;  }
    else if (bid < 256) { W=W_q;  Ph=Pqh;  Pl=Pql;  N=512; base=128; }
    else if (bid < 320) { W=W_c1; Ph=Pc1h; Pl=Pc1l; N=256; base=256; }
    else                { W=W_e1; Ph=Peh;  Pl=nullptr; N=256; base=320; }
    int g = (bid-base)*256 + threadIdx.x;
    int lane = g & 63, slot = g >> 6;
    int NT = N >> 4;
    int nt = slot % NT, kt = slot / NT;
    int krow = kt*32 + (lane>>4)*8, ncol = nt*16 + (lane&15);
    #pragma unroll
    for (int j=0;j<8;j++){
        float w = W[(size_t)(krow+j)*N + ncol];
        __bf16 hi = (__bf16)w;
        Ph[(size_t)g*8+j] = hi;
        if (Pl) Pl[(size_t)g*8+j] = (__bf16)(w - (float)hi);
    }
}

// ---------------------------------------------------------------------------
// K1: per-batch: gather q0..q3; ve[b][h] = W_e2[h,:]·q2 (wave-coalesced); se[b]=b_e2·q2
// ---------------------------------------------------------------------------
__global__ __launch_bounds__(256) void k_prep(
    const float* __restrict__ word_emb, const int* __restrict__ program_inputs,
    const float* __restrict__ W_e2, const float* __restrict__ b_e2,
    float* __restrict__ qws, float* __restrict__ ve, float* __restrict__ se)
{
    int b = blockIdx.x, t = threadIdx.x, wv = t>>6, lane = t&63;
    int idx[4];
    #pragma unroll
    for (int k=0;k<4;k++) idx[k] = program_inputs[b*LQ + k];
    #pragma unroll
    for (int k=0;k<4;k++){
        qws[((size_t)(b*4+k))*DV + t]       = word_emb[(size_t)idx[k]*DV + t];
        qws[((size_t)(b*4+k))*DV + t + 256] = word_emb[(size_t)idx[k]*DV + t + 256];
    }
    // q2 slice held in registers (lane owns 8 consecutive elems)
    const float* q2p = word_emb + (size_t)idx[2]*DV + lane*8;
    float4 qa = *(const float4*)q2p, qb = *(const float4*)(q2p+4);
    // wave wv handles rows h = wv*64 .. +63; coalesced 2KB row reads
    for (int i=0;i<64;i++){
        int h = wv*64 + i;
        const float* wr = W_e2 + (size_t)h*DV + lane*8;
        float4 a = *(const float4*)wr, c = *(const float4*)(wr+4);
        float p = a.x*qa.x + a.y*qa.y + a.z*qa.z + a.w*qa.w
                + c.x*qb.x + c.y*qb.y + c.z*qb.z + c.w*qb.w;
        #pragma unroll
        for (int off=32; off; off>>=1) p += __shfl_xor(p, off, 64);
        if (lane==0) ve[b*HH + h] = p;
    }
    // se = b_e2 . q2
    float pp = b_e2[t]*word_emb[(size_t)idx[2]*DV + t]
             + b_e2[t+256]*word_emb[(size_t)idx[2]*DV + t + 256];
    __shared__ float red[4];
    #pragma unroll
    for (int off=32; off; off>>=1) pp += __shfl_down(pp, off, 64);
    if ((t&63)==0) red[t>>6] = pp;
    __syncthreads();
    if (t==0) se[b] = red[0]+red[1]+red[2]+red[3];
}

// ---------------------------------------------------------------------------
// K2: fused node MLP: nf = relu(X@W1+b1)@W2+b2.  16 rows/block, 288 blocks.
// Split-bf16 (hi/lo) 3-term MFMA emulation, fp32 accumulate (~2^-18 rel err).
// A operands staged in LDS in A-fragment layout [kt][lane][8] (conflict-free).
// ---------------------------------------------------------------------------
__global__ __launch_bounds__(256) void k_node(
    const float* __restrict__ X,
    const __bf16* __restrict__ W1h, const __bf16* __restrict__ W1l,
    const float* __restrict__ b1,
    const __bf16* __restrict__ W2h, const __bf16* __restrict__ W2l,
    const float* __restrict__ b2,
    float* __restrict__ nf)
{
    __shared__ __align__(16) __bf16 xh[16*512];   // 16 KB, frag layout K=512
    __shared__ __align__(16) __bf16 xl[16*512];   // 16 KB
    __shared__ __align__(16) __bf16 hh[8*64*8];   // 8 KB, frag layout K=256
    __shared__ __align__(16) __bf16 hl[8*64*8];   // 8 KB
    int r0 = blockIdx.x*16, t = threadIdx.x, wv = t>>6, lane = t&63;

    // stage X[16x512] fp32 -> hi/lo bf16 A-frag layout
    #pragma unroll
    for (int i=0;i<8;i++){
        int linear = t + i*256;                    // 2048 float4
        int row = linear >> 7, c4 = (linear & 127)*4;
        float4 f = *(const float4*)(X + (size_t)(r0+row)*DF + c4);
        int kt = c4 >> 5, lane2 = ((c4 & 31) >> 3)*16 + row, j2 = c4 & 7;
        bf16_4 h, l;
        h[0]=(__bf16)f.x; l[0]=(__bf16)(f.x-(float)h[0]);
        h[1]=(__bf16)f.y; l[1]=(__bf16)(f.y-(float)h[1]);
        h[2]=(__bf16)f.z; l[2]=(__bf16)(f.z-(float)h[2]);
        h[3]=(__bf16)f.w; l[3]=(__bf16)(f.w-(float)h[3]);
        int off = (kt*64 + lane2)*8 + j2;
        *(bf16_4*)&xh[off] = h;
        *(bf16_4*)&xl[off] = l;
    }
    __syncthreads();

    // GEMM1: hid[16x256] = relu(X @ W1 + b1). Wave wv: cols wv*64..+63.
    f32_4 zero = {0.f,0.f,0.f,0.f};
    f32_4 acc1[4];
    #pragma unroll
    for (int nt=0;nt<4;nt++) acc1[nt] = zero;
    for (int kt=0; kt<16; kt++){
        bf16_8 ah = *(const bf16_8*)&xh[(kt*64+lane)*8];
        bf16_8 al = *(const bf16_8*)&xl[(kt*64+lane)*8];
        #pragma unroll
        for (int nt=0;nt<4;nt++){
            size_t bo = ((size_t)(kt*16 + wv*4+nt)*64 + lane)*8;
            bf16_8 bh = *(const bf16_8*)(W1h + bo);
            bf16_8 bl = *(const bf16_8*)(W1l + bo);
            acc1[nt] = __builtin_amdgcn_mfma_f32_16x16x32_bf16(ah, bh, acc1[nt], 0,0,0);
            acc1[nt] = __builtin_amdgcn_mfma_f32_16x16x32_bf16(al, bh, acc1[nt], 0,0,0);
            acc1[nt] = __builtin_amdgcn_mfma_f32_16x16x32_bf16(ah, bl, acc1[nt], 0,0,0);
        }
    }
    // epilogue1: relu(+b1), hi/lo -> hid frag layout
    int q = lane>>4, c = lane&15;
    #pragma unroll
    for (int nt=0;nt<4;nt++){
        int col = wv*64 + nt*16 + c;
        float bias = b1[col];
        int kt2 = col>>5, j2 = col&7;
        int lbase = ((col&31)>>3)*16;
        #pragma unroll
        for (int r=0;r<4;r++){
            int row = q*4 + r;
            float v = reluf_(acc1[nt][r] + bias);
            __bf16 hi = (__bf16)v;
            int off = (kt2*64 + lbase + row)*8 + j2;
            hh[off] = hi;
            hl[off] = (__bf16)(v - (float)hi);
        }
    }
    __syncthreads();

    // GEMM2: nf[16x512] = hid @ W2 + b2. Wave wv: cols wv*128..+127.
    f32_4 acc2[8];
    #pragma unroll
    for (int nt=0;nt<8;nt++) acc2[nt] = zero;
    for (int kt=0; kt<8; kt++){
        bf16_8 ah = *(const bf16_8*)&hh[(kt*64+lane)*8];
        bf16_8 al = *(const bf16_8*)&hl[(kt*64+lane)*8];
        #pragma unroll
        for (int nt=0;nt<8;nt++){
            size_t bo = ((size_t)(kt*32 + wv*8+nt)*64 + lane)*8;
            bf16_8 bh = *(const bf16_8*)(W2h + bo);
            bf16_8 bl = *(const bf16_8*)(W2l + bo);
            acc2[nt] = __builtin_amdgcn_mfma_f32_16x16x32_bf16(ah, bh, acc2[nt], 0,0,0);
            acc2[nt] = __builtin_amdgcn_mfma_f32_16x16x32_bf16(al, bh, acc2[nt], 0,0,0);
            acc2[nt] = __builtin_amdgcn_mfma_f32_16x16x32_bf16(ah, bl, acc2[nt], 0,0,0);
        }
    }
    #pragma unroll
    for (int nt=0;nt<8;nt++){
        int col = wv*128 + nt*16 + c;
        float bias = b2[col];
        #pragma unroll
        for (int r=0;r<4;r++){
            int row = q*4 + r;
            nf[(size_t)(r0+row)*DV + col] = acc2[nt][r] + bias;
        }
    }
}

// ---------------------------------------------------------------------------
// K4: edge kernel (unchanged from R1). 48 edges/block, bf16 MFMA.
// ---------------------------------------------------------------------------
__global__ __launch_bounds__(256) void k_edge(
    const float* __restrict__ E, const __bf16* __restrict__ Wp,
    const float* __restrict__ b_e1, const float* __restrict__ ve,
    const float* __restrict__ se, float* __restrict__ weit)
{
    constexpr int LDW = DE + 8;
    __shared__ __align__(16) __bf16 as[48*LDW];
    __shared__ float red[4][48];
    int bx = blockIdx.x;
    int b = bx / 27, tile = bx % 27;
    int e0 = tile*48;
    int t = threadIdx.x, wv = t>>6, lane = t&63;
    const float* Eb = E + ((size_t)b*NE + e0)*DE;

    #pragma unroll
    for (int i=0;i<6;i++){
        int cch = t + i*256;
        int row = cch >> 5, cc = cch & 31;
        const float* src = Eb + (size_t)row*DE + cc*8;
        float4 f0 = *(const float4*)(src);
        float4 f1 = *(const float4*)(src+4);
        bf16_8 v;
        v[0]=(__bf16)f0.x; v[1]=(__bf16)f0.y; v[2]=(__bf16)f0.z; v[3]=(__bf16)f0.w;
        v[4]=(__bf16)f1.x; v[5]=(__bf16)f1.y; v[6]=(__bf16)f1.z; v[7]=(__bf16)f1.w;
        *(bf16_8*)&as[row*LDW + cc*8] = v;
    }
    __syncthreads();

    f32_4 zero = {0.f,0.f,0.f,0.f};
    f32_4 acc[3][4];
    #pragma unroll
    for (int mt=0;mt<3;mt++)
        #pragma unroll
        for (int nt=0;nt<4;nt++) acc[mt][nt] = zero;

    int arow = lane & 15, ako = (lane>>4)*8;
    for (int kt=0; kt<8; kt++){
        bf16_8 afrag[3];
        #pragma unroll
        for (int mt=0;mt<3;mt++)
            afrag[mt] = *(const bf16_8*)&as[(mt*16 + arow)*LDW + kt*32 + ako];
        #pragma unroll
        for (int nt=0;nt<4;nt++){
            bf16_8 bfrag = *(const bf16_8*)(Wp + ((size_t)(kt*16 + (wv*4+nt))*64 + lane)*8);
            #pragma unroll
            for (int mt=0;mt<3;mt++)
                acc[mt][nt] = __builtin_amdgcn_mfma_f32_16x16x32_bf16(afrag[mt], bfrag, acc[mt][nt], 0,0,0);
        }
    }

    float ves[4], be[4];
    #pragma unroll
    for (int nt=0;nt<4;nt++){
        int n = wv*64 + nt*16 + (lane&15);
        ves[nt] = ve[b*HH + n];
        be[nt]  = b_e1[n];
    }
    float part[3][4];
    #pragma unroll
    for (int mt=0;mt<3;mt++)
        #pragma unroll
        for (int r=0;r<4;r++){
            float s = 0.f;
            #pragma unroll
            for (int nt=0;nt<4;nt++)
                s = fmaf(reluf_(acc[mt][nt][r] + be[nt]), ves[nt], s);
            part[mt][r] = s;
        }
    #pragma unroll
    for (int off=1; off<16; off<<=1)
        #pragma unroll
        for (int mt=0;mt<3;mt++)
            #pragma unroll
            for (int r=0;r<4;r++)
                part[mt][r] += __shfl_xor(part[mt][r], off, 64);
    if ((lane&15)==0){
        int g = lane>>4;
        #pragma unroll
        for (int mt=0;mt<3;mt++)
            #pragma unroll
            for (int r=0;r<4;r++)
                red[wv][mt*16 + g*4 + r] = part[mt][r];
    }
    __syncthreads();
    if (t < 48){
        float logit = red[0][t]+red[1][t]+red[2][t]+red[3][t] + se[b];
        weit[(size_t)b*NE + e0 + t] = sigmoidf_(logit * SCALE);
    }
}

// ---------------------------------------------------------------------------
// K5a: per-batch attention chain -> x = (pooled * q0) into xws [B,DV]
// ---------------------------------------------------------------------------
__global__ __launch_bounds__(256) void k_attn(
    const float* __restrict__ nf, const float* __restrict__ qws,
    const float* __restrict__ weit, float* __restrict__ xws)
{
    int b = blockIdx.x, t = threadIdx.x;
    int wv = t>>6, lane = t&63;
    __shared__ float a1[NN], a2[NN], a3[NN];
    __shared__ float denom;
    const float* nfb = nf + (size_t)b*NN*DV;
    const float* q0 = qws + ((size_t)(b*4+0))*DV;
    const float* q1 = qws + ((size_t)(b*4+1))*DV;
    const float* q3 = qws + ((size_t)(b*4+3))*DV;

    for (int i=wv; i<NN; i+=4){
        const float* row = nfb + (size_t)i*DV + lane*8;
        const float* qq  = q3 + lane*8;
        float4 x0 = *(const float4*)row, x1 = *(const float4*)(row+4);
        float4 y0 = *(const float4*)qq,  y1 = *(const float4*)(qq+4);
        float p = x0.x*y0.x + x0.y*y0.y + x0.z*y0.z + x0.w*y0.w
                + x1.x*y1.x + x1.y*y1.y + x1.z*y1.z + x1.w*y1.w;
        #pragma unroll
        for (int off=32; off; off>>=1) p += __shfl_xor(p, off, 64);
        if (lane==0) a1[i] = sigmoidf_(p*SCALE);
    }
    __syncthreads();
    if (t < NN){
        const float* wrow = weit + (size_t)b*NE;
        float s = 0.f;
        for (int i=0;i<NN;i++) s = fmaf(a1[i], wrow[i*NN + t], s);
        a2[t] = fminf(fmaxf(s, 0.f), 1.f);
    }
    __syncthreads();
    for (int i=wv; i<NN; i+=4){
        const float* row = nfb + (size_t)i*DV + lane*8;
        const float* qq  = q1 + lane*8;
        float4 x0 = *(const float4*)row, x1 = *(const float4*)(row+4);
        float4 y0 = *(const float4*)qq,  y1 = *(const float4*)(qq+4);
        float p = x0.x*y0.x + x0.y*y0.y + x0.z*y0.z + x0.w*y0.w
                + x1.x*y1.x + x1.y*y1.y + x1.z*y1.z + x1.w*y1.w;
        #pragma unroll
        for (int off=32; off; off>>=1) p += __shfl_xor(p, off, 64);
        if (lane==0) a3[i] = a2[i]*sigmoidf_(p*SCALE);
    }
    __syncthreads();
    if (t==0){
        float s = 0.f;
        for (int i=0;i<NN;i++) s += a3[i];
        denom = 1.f/(s + 1e-8f);
    }
    __syncthreads();
    float p0=0.f, p1=0.f;
    for (int i=0;i<NN;i++){
        float a = a3[i]*denom;
        p0 = fmaf(a, nfb[(size_t)i*DV + t], p0);
        p1 = fmaf(a, nfb[(size_t)i*DV + t + 256], p1);
    }
    xws[(size_t)b*DV + t]       = p0*q0[t];
    xws[(size_t)b*DV + t + 256] = p1*q0[t+256];
}

// ---------------------------------------------------------------------------
// K5b: head GEMM chain: out = relu(relu(x@W_q+b_q)@W_c1+b_c1)@W_c2+b_c2
// 8 blocks x 16 rows. Split-bf16 3-term MFMA. 64 KB LDS, region-reused.
// ---------------------------------------------------------------------------
__global__ __launch_bounds__(256) void k_head(
    const float* __restrict__ xws,
    const __bf16* __restrict__ Wqh, const __bf16* __restrict__ Wql,
    const float* __restrict__ b_q,
    const __bf16* __restrict__ Wc1h, const __bf16* __restrict__ Wc1l,
    const float* __restrict__ b_c1,
    const float* __restrict__ W_c2, const float* __restrict__ b_c2,
    float* __restrict__ out)
{
    __shared__ __align__(16) char smem[65536];
    __bf16* xh = (__bf16*)smem;             // [16 KB] x frag, K=512
    __bf16* xl = xh + 8192;                 // [16 KB]
    __bf16* oh = (__bf16*)(smem + 32768);   // [16 KB] o frag, K=512
    __bf16* ol = oh + 8192;                 // [16 KB]
    float* hbuf  = (float*)smem;            // [16x264 fp32, 16.9 KB] aliases x (dead after GEMM1)
    float* wc2s  = (float*)(smem + 32768);  // [28 KB] aliases o (dead after GEMM2)

    int r0 = blockIdx.x*16, t = threadIdx.x, wv = t>>6, lane = t&63;
    int q = lane>>4, c = lane&15;

    // stage x[16x512] -> hi/lo frag layout
    #pragma unroll
    for (int i=0;i<8;i++){
        int linear = t + i*256;
        int row = linear >> 7, c4 = (linear & 127)*4;
        float4 f = *(const float4*)(xws + (size_t)(r0+row)*DV + c4);
        int kt = c4 >> 5, lane2 = ((c4 & 31) >> 3)*16 + row, j2 = c4 & 7;
        bf16_4 h, l;
        h[0]=(__bf16)f.x; l[0]=(__bf16)(f.x-(float)h[0]);
        h[1]=(__bf16)f.y; l[1]=(__bf16)(f.y-(float)h[1]);
        h[2]=(__bf16)f.z; l[2]=(__bf16)(f.z-(float)h[2]);
        h[3]=(__bf16)f.w; l[3]=(__bf16)(f.w-(float)h[3]);
        int off = (kt*64 + lane2)*8 + j2;
        *(bf16_4*)&xh[off] = h;
        *(bf16_4*)&xl[off] = l;
    }
    __syncthreads();

    // GEMM1: o[16x512] = relu(x @ W_q + b_q). Wave: 128 cols.
    f32_4 zero = {0.f,0.f,0.f,0.f};
    f32_4 acc[8];
    #pragma unroll
    for (int nt=0;nt<8;nt++) acc[nt] = zero;
    for (int kt=0; kt<16; kt++){
        bf16_8 ah = *(const bf16_8*)&xh[(kt*64+lane)*8];
        bf16_8 al = *(const bf16_8*)&xl[(kt*64+lane)*8];
        #pragma unroll
        for (int nt=0;nt<8;nt++){
            size_t bo = ((size_t)(kt*32 + wv*8+nt)*64 + lane)*8;
            bf16_8 bh = *(const bf16_8*)(Wqh + bo);
            bf16_8 bl = *(const bf16_8*)(Wql + bo);
            acc[nt] = __builtin_amdgcn_mfma_f32_16x16x32_bf16(ah, bh, acc[nt], 0,0,0);
            acc[nt] = __builtin_amdgcn_mfma_f32_16x16x32_bf16(al, bh, acc[nt], 0,0,0);
            acc[nt] = __builtin_amdgcn_mfma_f32_16x16x32_bf16(ah, bl, acc[nt], 0,0,0);
        }
    }
    #pragma unroll
    for (int nt=0;nt<8;nt++){
        int col = wv*128 + nt*16 + c;
        float bias = b_q[col];
        int kt2 = col>>5, j2 = col&7;
        int lbase = ((col&31)>>3)*16;
        #pragma unroll
        for (int r=0;r<4;r++){
            int row = q*4 + r;
            float v = reluf_(acc[nt][r] + bias);
            __bf16 hi = (__bf16)v;
            int off = (kt2*64 + lbase + row)*8 + j2;
            oh[off] = hi;
            ol[off] = (__bf16)(v - (float)hi);
        }
    }
    __syncthreads();

    // GEMM2: h[16x256] = relu(o @ W_c1 + b_c1). Wave: 64 cols.
    f32_4 acc2[4];
    #pragma unroll
    for (int nt=0;nt<4;nt++) acc2[nt] = zero;
    for (int kt=0; kt<16; kt++){
        bf16_8 ah = *(const bf16_8*)&oh[(kt*64+lane)*8];
        bf16_8 al = *(const bf16_8*)&ol[(kt*64+lane)*8];
        #pragma unroll
        for (int nt=0;nt<4;nt++){
            size_t bo = ((size_t)(kt*16 + wv*4+nt)*64 + lane)*8;
            bf16_8 bh = *(const bf16_8*)(Wc1h + bo);
            bf16_8 bl = *(const bf16_8*)(Wc1l + bo);
            acc2[nt] = __builtin_amdgcn_mfma_f32_16x16x32_bf16(ah, bh, acc2[nt], 0,0,0);
            acc2[nt] = __builtin_amdgcn_mfma_f32_16x16x32_bf16(al, bh, acc2[nt], 0,0,0);
            acc2[nt] = __builtin_amdgcn_mfma_f32_16x16x32_bf16(ah, bl, acc2[nt], 0,0,0);
        }
    }
    __syncthreads();   // all GEMM2 reads of o done before wc2s overwrite; x dead -> hbuf ok
    #pragma unroll
    for (int nt=0;nt<4;nt++){
        int col = wv*64 + nt*16 + c;
        float bias = b_c1[col];
        #pragma unroll
        for (int r=0;r<4;r++){
            int row = q*4 + r;
            hbuf[row*264 + col] = reluf_(acc2[nt][r] + bias);
        }
    }
    // stage W_c2 [256x28] into LDS (aliases o region)
    for (int i=t; i<1792; i+=256)
        ((float4*)wc2s)[i] = ((const float4*)W_c2)[i];
    __syncthreads();

    // GEMM3: out[16x28] = h @ W_c2 + b_c2 (VALU from LDS)
    for (int idx=t; idx<16*NCC; idx+=256){
        int row = idx / NCC, cc = idx - row*NCC;
        float s = b_c2[cc];
        for (int k=0;k<HH;k++)
            s = fmaf(hbuf[row*264 + k], wc2s[k*NCC + cc], s);
        out[(size_t)(r0+row)*NCC + cc] = s;
    }
}

// ---------------------------------------------------------------------------
extern "C" void kernel_launch(void* const* d_in, const int* in_sizes, int n_in,
                              void* d_out, int out_size, void* d_ws, size_t ws_size,
                              hipStream_t stream)
{
    const float* node_feats = (const float*)d_in[0];
    const float* edge_feats = (const float*)d_in[1];
    const float* W_n1 = (const float*)d_in[2];
    const float* b_n1 = (const float*)d_in[3];
    const float* W_n2 = (const float*)d_in[4];
    const float* b_n2 = (const float*)d_in[5];
    const float* W_e1 = (const float*)d_in[6];
    const float* b_e1 = (const float*)d_in[7];
    const float* W_e2 = (const float*)d_in[8];
    const float* b_e2 = (const float*)d_in[9];
    const float* W_q  = (const float*)d_in[10];
    const float* b_q  = (const float*)d_in[11];
    const float* W_c1 = (const float*)d_in[12];
    const float* b_c1 = (const float*)d_in[13];
    const float* W_c2 = (const float*)d_in[14];
    const float* b_c2 = (const float*)d_in[15];
    const float* word_emb = (const float*)d_in[16];
    const int* program_inputs = (const int*)d_in[18];

    // workspace layout (all chunks 256B-aligned)
    char* ws = (char*)d_ws;
    float* qws  = (float*)ws; ws += (size_t)BB*4*DV*4;        // 1 MB
    float* ve   = (float*)ws; ws += (size_t)BB*HH*4;          // 128 KB
    float* se   = (float*)ws; ws += 512;
    float* xws  = (float*)ws; ws += (size_t)BB*DV*4;          // 256 KB
    __bf16* Pn1h = (__bf16*)ws; ws += (size_t)DF*HH*2;        // 256 KB
    __bf16* Pn1l = (__bf16*)ws; ws += (size_t)DF*HH*2;
    __bf16* Pn2h = (__bf16*)ws; ws += (size_t)HH*DV*2;
    __bf16* Pn2l = (__bf16*)ws; ws += (size_t)HH*DV*2;
    __bf16* Pqh  = (__bf16*)ws; ws += (size_t)DV*DV*2;        // 512 KB
    __bf16* Pql  = (__bf16*)ws; ws += (size_t)DV*DV*2;
    __bf16* Pc1h = (__bf16*)ws; ws += (size_t)DV*HH*2;
    __bf16* Pc1l = (__bf16*)ws; ws += (size_t)DV*HH*2;
    __bf16* Peh  = (__bf16*)ws; ws += (size_t)DE*HH*2;        // 128 KB
    float* nf   = (float*)ws; ws += (size_t)BB*NN*DV*4;       // 9 MB
    float* weit = (float*)ws; ws += (size_t)BB*NE*4;          // 648 KB

    k_pack_all<<<352, 256, 0, stream>>>(W_n1, W_n2, W_q, W_c1, W_e1,
                                        Pn1h, Pn1l, Pn2h, Pn2l, Pqh, Pql, Pc1h, Pc1l, Peh);
    k_prep<<<BB, 256, 0, stream>>>(word_emb, program_inputs, W_e2, b_e2, qws, ve, se);
    k_node<<<(BB*NN)/16, 256, 0, stream>>>(node_feats, Pn1h, Pn1l, b_n1, Pn2h, Pn2l, b_n2, nf);
    k_edge<<<BB*27, 256, 0, stream>>>(edge_feats, Peh, b_e1, ve, se, weit);
    k_attn<<<BB, 256, 0, stream>>>(nf, qws, weit, xws);
    k_head<<<BB/16, 256, 0, stream>>>(xws, Pqh, Pql, b_q, Pc1h, Pc1l, b_c1, W_c2, b_c2,
                                      (float*)d_out);
}